// Round 1
// baseline (567.212 us; speedup 1.0000x reference)
//
#include <hip/hip_runtime.h>

#define B_ 48
#define N_ 512
#define C_ 64
#define K_ 5
#define O_ 64
#define EPSF 1e-9f

#define TI 16
#define TJ 64
#define LPAD 68   // padded row (floats): bank stride 4, keeps float4 alignment

// ---------------- kernel A: per-(b,n) attention scores s = (si_r, si_i, sj_r, sj_i)
__global__ __launch_bounds__(64) void k_s(
    const float* __restrict__ Xr, const float* __restrict__ Xi,
    const float* __restrict__ War, const float* __restrict__ Wai,
    float4* __restrict__ s_out)
{
  int bn = blockIdx.x;
  int c = threadIdx.x;
  float xr = Xr[bn * C_ + c];
  float xi = Xi[bn * C_ + c];
  float w1r = War[c], w2r = War[C_ + c];
  float w1i = Wai[c], w2i = Wai[C_ + c];
  float sir = xr * w1r - xi * w1i;
  float sii = xr * w1i + xi * w1r;
  float sjr = xr * w2r - xi * w2i;
  float sji = xr * w2i + xi * w2r;
#pragma unroll
  for (int off = 32; off >= 1; off >>= 1) {
    sir += __shfl_down(sir, off);
    sii += __shfl_down(sii, off);
    sjr += __shfl_down(sjr, off);
    sji += __shfl_down(sji, off);
  }
  if (c == 0) s_out[bn] = make_float4(sir, sii, sjr, sji);
}

// ---------------- kernel B: per-(b,i) softmax stats (max_r, 1/sum_r, max_i, 1/sum_i)
__global__ __launch_bounds__(512) void k_stats(
    const float4* __restrict__ s,
    const float* __restrict__ ba_r_p, const float* __restrict__ ba_i_p,
    const float* __restrict__ modb_p,
    float4* __restrict__ stats)
{
  int bi = blockIdx.x;        // b*N + i
  int b = bi >> 9;
  int j = threadIdx.x;
  float ba_r = ba_r_p[0], ba_i = ba_i_p[0], modb = modb_p[0];
  float4 si = s[bi];
  float4 sj = s[(b << 9) + j];
  float scr = si.x + sj.z + ba_r;
  float sci = si.y + sj.w + ba_i;
  float mag = sqrtf(scr * scr + sci * sci);
  float scale = fmaxf(mag + modb, 0.0f) / (mag + EPSF);
  scr *= scale;
  sci *= scale;

  __shared__ float redA[8], redB[8];
  float mr = scr, mi = sci;
#pragma unroll
  for (int off = 32; off >= 1; off >>= 1) {
    mr = fmaxf(mr, __shfl_down(mr, off));
    mi = fmaxf(mi, __shfl_down(mi, off));
  }
  int wid = j >> 6, lane = j & 63;
  if (lane == 0) { redA[wid] = mr; redB[wid] = mi; }
  __syncthreads();
  mr = redA[0]; mi = redB[0];
#pragma unroll
  for (int w = 1; w < 8; ++w) { mr = fmaxf(mr, redA[w]); mi = fmaxf(mi, redB[w]); }
  __syncthreads();
  float er = __expf(scr - mr), ei = __expf(sci - mi);
#pragma unroll
  for (int off = 32; off >= 1; off >>= 1) {
    er += __shfl_down(er, off);
    ei += __shfl_down(ei, off);
  }
  if (lane == 0) { redA[wid] = er; redB[wid] = ei; }
  __syncthreads();
  if (j == 0) {
    float sr = 0.f, ssi = 0.f;
#pragma unroll
    for (int w = 0; w < 8; ++w) { sr += redA[w]; ssi += redB[w]; }
    stats[bi] = make_float4(mr, 1.0f / sr, mi, 1.0f / ssi);
  }
}

// ---------------- kernel C: fused a-recompute + L-formation + LX matmul + W epilogue
__global__ __launch_bounds__(256, 2) void k_main(
    const float* __restrict__ Xr, const float* __restrict__ Xi,
    const float* __restrict__ lapr, const float* __restrict__ lapi,
    const float4* __restrict__ s, const float4* __restrict__ stats,
    const float* __restrict__ ba_r_p, const float* __restrict__ ba_i_p,
    const float* __restrict__ modb_p,
    const float* __restrict__ Wr, const float* __restrict__ Wi,
    float* __restrict__ out_r, float* __restrict__ out_i)
{
  __shared__ __align__(16) float smem[19072]; // XR 4096 | XI 4096 | LR 5440 | LI 5440
  __shared__ float sh_row[TI][6];
  __shared__ float sh_sj[TJ][2];

  const int t  = threadIdx.x;
  const int it = blockIdx.x;        // i-tile 0..31
  const int b  = blockIdx.y;        // 0..47
  const int il = t >> 4;            // 0..15
  const int q4 = (t & 15) * 4;      // j0 in staging, c4 in inner loop, o4 in epilogue

  const float ba_r = ba_r_p[0], ba_i = ba_i_p[0], modb = modb_p[0];

  if (t < TI) {
    int gi = it * TI + t;
    float4 sv = s[b * N_ + gi];
    float4 st = stats[b * N_ + gi];
    sh_row[t][0] = sv.x + ba_r;
    sh_row[t][1] = sv.y + ba_i;
    sh_row[t][2] = st.x;
    sh_row[t][3] = st.y;
    sh_row[t][4] = st.z;
    sh_row[t][5] = st.w;
  }

  float accR[K_][4], accI[K_][4];
#pragma unroll
  for (int k = 0; k < K_; ++k)
#pragma unroll
    for (int u = 0; u < 4; ++u) { accR[k][u] = 0.f; accI[k][u] = 0.f; }

  float4* shXr4 = (float4*)&smem[0];      // [TJ][16] float4
  float4* shXi4 = (float4*)&smem[4096];
  float*  shLr  = &smem[8192];            // [K_][TI][LPAD]
  float*  shLi  = &smem[13632];

  for (int jt = 0; jt < N_ / TJ; ++jt) {
    __syncthreads(); // previous iteration's LDS reads complete
    {
      const float4* gXr = (const float4*)&Xr[(b * N_ + jt * TJ) * C_];
      const float4* gXi = (const float4*)&Xi[(b * N_ + jt * TJ) * C_];
#pragma unroll
      for (int p = 0; p < 4; ++p) {
        int idx = t + p * 256;
        shXr4[idx] = gXr[idx];
        shXi4[idx] = gXi[idx];
      }
    }
    if (t < TJ) {
      float4 sv = s[b * N_ + jt * TJ + t];
      sh_sj[t][0] = sv.z;
      sh_sj[t][1] = sv.w;
    }
    __syncthreads();
    // form L = lap * a on the fly while staging (lap read exactly once from HBM)
    {
      int gi = it * TI + il;
      int gj = jt * TJ + q4;
      float ar[4], ai[4];
      float sir = sh_row[il][0], sii = sh_row[il][1];
      float maxr = sh_row[il][2], rsr = sh_row[il][3];
      float maxi = sh_row[il][4], rsi = sh_row[il][5];
#pragma unroll
      for (int jj = 0; jj < 4; ++jj) {
        float scr = sir + sh_sj[q4 + jj][0];
        float sci = sii + sh_sj[q4 + jj][1];
        float mag = sqrtf(scr * scr + sci * sci);
        float scale = fmaxf(mag + modb, 0.0f) / (mag + EPSF);
        scr *= scale; sci *= scale;
        ar[jj] = __expf(scr - maxr) * rsr;
        ai[jj] = __expf(sci - maxi) * rsi;
      }
      size_t gbase = ((size_t)(b * K_) * N_ + gi) * N_ + gj;
#pragma unroll
      for (int k = 0; k < K_; ++k) {
        float4 l_r = *(const float4*)&lapr[gbase + (size_t)k * N_ * N_];
        float4 l_i = *(const float4*)&lapi[gbase + (size_t)k * N_ * N_];
        float4 vr, vi;
        vr.x = l_r.x * ar[0] - l_i.x * ai[0];  vi.x = l_r.x * ai[0] + l_i.x * ar[0];
        vr.y = l_r.y * ar[1] - l_i.y * ai[1];  vi.y = l_r.y * ai[1] + l_i.y * ar[1];
        vr.z = l_r.z * ar[2] - l_i.z * ai[2];  vi.z = l_r.z * ai[2] + l_i.z * ar[2];
        vr.w = l_r.w * ar[3] - l_i.w * ai[3];  vi.w = l_r.w * ai[3] + l_i.w * ar[3];
        *(float4*)&shLr[k * (TI * LPAD) + il * LPAD + q4] = vr;
        *(float4*)&shLi[k * (TI * LPAD) + il * LPAD + q4] = vi;
      }
    }
    __syncthreads();
    // register-blocked accumulate: thread owns (row il, cols q4..q4+3) for all k, r/i
    {
      const float* lrb = &shLr[il * LPAD];
      const float* lib = &shLi[il * LPAD];
#pragma unroll 2
      for (int j = 0; j < TJ; ++j) {
        float4 xr = shXr4[j * 16 + (t & 15)];
        float4 xi = shXi4[j * 16 + (t & 15)];
#pragma unroll
        for (int k = 0; k < K_; ++k) {
          float lr = lrb[k * (TI * LPAD) + j];
          float li = lib[k * (TI * LPAD) + j];
          accR[k][0] = fmaf(lr, xr.x, fmaf(-li, xi.x, accR[k][0]));
          accR[k][1] = fmaf(lr, xr.y, fmaf(-li, xi.y, accR[k][1]));
          accR[k][2] = fmaf(lr, xr.z, fmaf(-li, xi.z, accR[k][2]));
          accR[k][3] = fmaf(lr, xr.w, fmaf(-li, xi.w, accR[k][3]));
          accI[k][0] = fmaf(lr, xi.x, fmaf(li, xr.x, accI[k][0]));
          accI[k][1] = fmaf(lr, xi.y, fmaf(li, xr.y, accI[k][1]));
          accI[k][2] = fmaf(lr, xi.z, fmaf(li, xr.z, accI[k][2]));
          accI[k][3] = fmaf(lr, xi.w, fmaf(li, xr.w, accI[k][3]));
        }
      }
    }
  }

  // ---- epilogue: out[i,o] = sum_{k,c} LX_r*W_r - LX_i*W_i  (and imag)
  __syncthreads();
  float* shLXr = &smem[0];
  float* shLXi = &smem[5440];
#pragma unroll
  for (int k = 0; k < K_; ++k) {
    *(float4*)&shLXr[k * (TI * LPAD) + il * LPAD + q4] =
        make_float4(accR[k][0], accR[k][1], accR[k][2], accR[k][3]);
    *(float4*)&shLXi[k * (TI * LPAD) + il * LPAD + q4] =
        make_float4(accI[k][0], accI[k][1], accI[k][2], accI[k][3]);
  }
  __syncthreads();

  float or_[4] = {0.f, 0.f, 0.f, 0.f}, oi_[4] = {0.f, 0.f, 0.f, 0.f};
#pragma unroll
  for (int k = 0; k < K_; ++k) {
    const float* lxr = &shLXr[k * (TI * LPAD) + il * LPAD];
    const float* lxi = &shLXi[k * (TI * LPAD) + il * LPAD];
    const float4* wr4 = (const float4*)&Wr[k * C_ * O_];
    const float4* wi4 = (const float4*)&Wi[k * C_ * O_];
    for (int c = 0; c < C_; ++c) {
      float xr = lxr[c], xi = lxi[c];
      float4 wr = wr4[c * 16 + (t & 15)];
      float4 wi = wi4[c * 16 + (t & 15)];
      or_[0] = fmaf(xr, wr.x, fmaf(-xi, wi.x, or_[0]));
      or_[1] = fmaf(xr, wr.y, fmaf(-xi, wi.y, or_[1]));
      or_[2] = fmaf(xr, wr.z, fmaf(-xi, wi.z, or_[2]));
      or_[3] = fmaf(xr, wr.w, fmaf(-xi, wi.w, or_[3]));
      oi_[0] = fmaf(xr, wi.x, fmaf(xi, wr.x, oi_[0]));
      oi_[1] = fmaf(xr, wi.y, fmaf(xi, wr.y, oi_[1]));
      oi_[2] = fmaf(xr, wi.z, fmaf(xi, wr.z, oi_[2]));
      oi_[3] = fmaf(xr, wi.w, fmaf(xi, wr.w, oi_[3]));
    }
  }
  int gi = it * TI + il;
  *(float4*)&out_r[(b * N_ + gi) * O_ + q4] = make_float4(or_[0], or_[1], or_[2], or_[3]);
  *(float4*)&out_i[(b * N_ + gi) * O_ + q4] = make_float4(oi_[0], oi_[1], oi_[2], oi_[3]);
}

extern "C" void kernel_launch(void* const* d_in, const int* in_sizes, int n_in,
                              void* d_out, int out_size, void* d_ws, size_t ws_size,
                              hipStream_t stream) {
  const float* Xr   = (const float*)d_in[0];
  const float* Xi   = (const float*)d_in[1];
  const float* lapr = (const float*)d_in[2];
  const float* lapi = (const float*)d_in[3];
  const float* War  = (const float*)d_in[4];
  const float* Wai  = (const float*)d_in[5];
  const float* bar  = (const float*)d_in[6];
  const float* bai  = (const float*)d_in[7];
  const float* modb = (const float*)d_in[8];
  const float* Wr   = (const float*)d_in[9];
  const float* Wi   = (const float*)d_in[10];

  // ws: s (B*N float4 = 384KB) | stats (384KB)
  float4* s_ws     = (float4*)d_ws;
  float4* stats_ws = s_ws + B_ * N_;

  float* out_r = (float*)d_out;
  float* out_i = out_r + (size_t)B_ * N_ * O_;

  k_s<<<B_ * N_, 64, 0, stream>>>(Xr, Xi, War, Wai, s_ws);
  k_stats<<<B_ * N_, 512, 0, stream>>>(s_ws, bar, bai, modb, stats_ws);
  dim3 grid(N_ / TI, B_);
  k_main<<<grid, 256, 0, stream>>>(Xr, Xi, lapr, lapi, s_ws, stats_ws,
                                   bar, bai, modb, Wr, Wi, out_r, out_i);
}

// Round 2
// 310.061 us; speedup vs baseline: 1.8294x; 1.8294x over previous
//
#include <hip/hip_runtime.h>

#define EPSF 1e-9f

typedef __attribute__((ext_vector_type(8))) short short8;
typedef __attribute__((ext_vector_type(4))) float f32x4;
typedef __attribute__((ext_vector_type(4))) unsigned int u32x4;
typedef __attribute__((ext_vector_type(2))) unsigned int u32x2;

__device__ __forceinline__ unsigned pkbf(float lo, float hi) {
  unsigned r;
  asm("v_cvt_pk_bf16_f32 %0, %1, %2" : "=v"(r) : "v"(lo), "v"(hi));
  return r;
}
__device__ __forceinline__ short8 mk8(unsigned a, unsigned b, unsigned c, unsigned d) {
  u32x4 u = {a, b, c, d};
  return __builtin_bit_cast(short8, u);
}

// ---------------- k_s: s[b,n] = (si_r, si_i, sj_r, sj_i); 8 lanes per row
__global__ __launch_bounds__(256) void k_s(
    const float* __restrict__ Xr, const float* __restrict__ Xi,
    const float* __restrict__ War, const float* __restrict__ Wai,
    float4* __restrict__ s4, float2* __restrict__ sj2)
{
  int t = threadIdx.x;
  int nf = blockIdx.x * 32 + (t >> 3);   // flat b*512+n
  int c0 = (t & 7) * 8;
  const f32x4* xr = (const f32x4*)(Xr + (size_t)nf * 64 + c0);
  const f32x4* xi = (const f32x4*)(Xi + (size_t)nf * 64 + c0);
  const f32x4* w1r = (const f32x4*)(War + c0);
  const f32x4* w2r = (const f32x4*)(War + 64 + c0);
  const f32x4* w1i = (const f32x4*)(Wai + c0);
  const f32x4* w2i = (const f32x4*)(Wai + 64 + c0);
  float sir = 0.f, sii = 0.f, sjr = 0.f, sji = 0.f;
#pragma unroll
  for (int h = 0; h < 2; ++h) {
    f32x4 a = xr[h], bb = xi[h];
    f32x4 u1r = w1r[h], u1i = w1i[h], u2r = w2r[h], u2i = w2i[h];
#pragma unroll
    for (int e = 0; e < 4; ++e) {
      sir += a[e] * u1r[e] - bb[e] * u1i[e];
      sii += a[e] * u1i[e] + bb[e] * u1r[e];
      sjr += a[e] * u2r[e] - bb[e] * u2i[e];
      sji += a[e] * u2i[e] + bb[e] * u2r[e];
    }
  }
#pragma unroll
  for (int off = 1; off < 8; off <<= 1) {
    sir += __shfl_xor(sir, off);
    sii += __shfl_xor(sii, off);
    sjr += __shfl_xor(sjr, off);
    sji += __shfl_xor(sji, off);
  }
  if ((t & 7) == 0) {
    s4[nf] = make_float4(sir, sii, sjr, sji);
    sj2[nf] = make_float2(sjr, sji);
  }
}

// ---------------- k_stats: per-(b,i) (max_r, 1/sum_r, max_i, 1/sum_i)
__global__ __launch_bounds__(256) void k_stats(
    const float4* __restrict__ s4, const float2* __restrict__ sj2,
    const float* __restrict__ bar, const float* __restrict__ bai,
    const float* __restrict__ modbp, float4* __restrict__ stats)
{
  __shared__ float2 sh[512];
  int t = threadIdx.x;
  int b = blockIdx.x >> 4;
  int i0 = (blockIdx.x & 15) * 32;
  sh[t] = sj2[(size_t)b * 512 + t];
  sh[t + 256] = sj2[(size_t)b * 512 + t + 256];
  __syncthreads();
  float ba_r = bar[0], ba_i = bai[0], modb = modbp[0];
  int i = i0 + (t >> 3), jl = t & 7;
  float4 sv = s4[(size_t)b * 512 + i];
  float sirb = sv.x + ba_r, siib = sv.y + ba_i;
  float mr = -1e30f, mi = -1e30f;
  for (int jj = 0; jj < 64; ++jj) {
    float2 sj = sh[jl * 64 + jj];
    float scr = sirb + sj.x, sci = siib + sj.y;
    float mag = sqrtf(scr * scr + sci * sci);
    float sc = fmaxf(mag + modb, 0.f) * __builtin_amdgcn_rcpf(mag + EPSF);
    mr = fmaxf(mr, scr * sc);
    mi = fmaxf(mi, sci * sc);
  }
#pragma unroll
  for (int off = 1; off < 8; off <<= 1) {
    mr = fmaxf(mr, __shfl_xor(mr, off));
    mi = fmaxf(mi, __shfl_xor(mi, off));
  }
  float er = 0.f, ei = 0.f;
  for (int jj = 0; jj < 64; ++jj) {
    float2 sj = sh[jl * 64 + jj];
    float scr = sirb + sj.x, sci = siib + sj.y;
    float mag = sqrtf(scr * scr + sci * sci);
    float sc = fmaxf(mag + modb, 0.f) * __builtin_amdgcn_rcpf(mag + EPSF);
    er += __expf(scr * sc - mr);
    ei += __expf(sci * sc - mi);
  }
#pragma unroll
  for (int off = 1; off < 8; off <<= 1) {
    er += __shfl_xor(er, off);
    ei += __shfl_xor(ei, off);
  }
  if (jl == 0)
    stats[(size_t)b * 512 + i] = make_float4(mr, 1.f / er, mi, 1.f / ei);
}

// ---------------- k_y: Y[b,k] = X[b] @ W[k] (complex), written to ws in
// B-fragment layout, bf16: line = (((b*5+k)*2+part)*16+js)*4+osub, 64 lanes x 16B
__global__ __launch_bounds__(256) void k_y(
    const float* __restrict__ Xr, const float* __restrict__ Xi,
    const float* __restrict__ Wr, const float* __restrict__ Wi,
    u32x4* __restrict__ yfrag)
{
  __shared__ __align__(16) short WtR[64 * 72];     // [o][c] pad 72
  __shared__ __align__(16) short WtI[64 * 72];
  __shared__ __align__(16) short Yt[4][2][64 * 24]; // per-wave [o][jj] pad 24
  int bk = blockIdx.x;
  int b = bk / 5, k = bk % 5;
  int t = threadIdx.x;
  {
    int o = t & 63, cbase = (t >> 6) * 16;
    const float* wr = Wr + (size_t)k * 4096;
    const float* wi = Wi + (size_t)k * 4096;
#pragma unroll
    for (int cc = 0; cc < 16; cc += 2) {
      int c = cbase + cc;
      *(unsigned*)&WtR[o * 72 + c] = pkbf(wr[c * 64 + o], wr[(c + 1) * 64 + o]);
      *(unsigned*)&WtI[o * 72 + c] = pkbf(wi[c * 64 + o], wi[(c + 1) * 64 + o]);
    }
  }
  __syncthreads();
  int w = t >> 6, l = t & 63;
  int lane15 = l & 15, quad = l >> 4;
  short* ytR = &Yt[w][0][0];
  short* ytI = &Yt[w][1][0];
  for (int qq = 0; qq < 8; ++qq) {
    int q = w * 8 + qq;
    int j = q * 16 + lane15;
    const f32x4* pxr = (const f32x4*)(Xr + ((size_t)b * 512 + j) * 64 + quad * 8);
    const f32x4* pxi = (const f32x4*)(Xi + ((size_t)b * 512 + j) * 64 + quad * 8);
    f32x4 xr0 = pxr[0], xr1 = pxr[1], xr8 = pxr[8], xr9 = pxr[9];
    f32x4 xi0 = pxi[0], xi1 = pxi[1], xi8 = pxi[8], xi9 = pxi[9];
    short8 axr[2], axi[2];
    axr[0] = mk8(pkbf(xr0[0], xr0[1]), pkbf(xr0[2], xr0[3]), pkbf(xr1[0], xr1[1]), pkbf(xr1[2], xr1[3]));
    axr[1] = mk8(pkbf(xr8[0], xr8[1]), pkbf(xr8[2], xr8[3]), pkbf(xr9[0], xr9[1]), pkbf(xr9[2], xr9[3]));
    axi[0] = mk8(pkbf(xi0[0], xi0[1]), pkbf(xi0[2], xi0[3]), pkbf(xi1[0], xi1[1]), pkbf(xi1[2], xi1[3]));
    axi[1] = mk8(pkbf(xi8[0], xi8[1]), pkbf(xi8[2], xi8[3]), pkbf(xi9[0], xi9[1]), pkbf(xi9[2], xi9[3]));
    f32x4 aR1[4], aR2[4], aI[4];
#pragma unroll
    for (int os = 0; os < 4; ++os) {
      aR1[os] = f32x4{0.f, 0.f, 0.f, 0.f};
      aR2[os] = f32x4{0.f, 0.f, 0.f, 0.f};
      aI[os] = f32x4{0.f, 0.f, 0.f, 0.f};
    }
#pragma unroll
    for (int kc = 0; kc < 2; ++kc) {
#pragma unroll
      for (int os = 0; os < 4; ++os) {
        int widx = (os * 16 + lane15) * 72 + kc * 32 + quad * 8;
        short8 wrF = *(const short8*)&WtR[widx];
        short8 wiF = *(const short8*)&WtI[widx];
        aR1[os] = __builtin_amdgcn_mfma_f32_16x16x32_bf16(axr[kc], wrF, aR1[os], 0, 0, 0);
        aR2[os] = __builtin_amdgcn_mfma_f32_16x16x32_bf16(axi[kc], wiF, aR2[os], 0, 0, 0);
        aI[os]  = __builtin_amdgcn_mfma_f32_16x16x32_bf16(axr[kc], wiF, aI[os], 0, 0, 0);
        aI[os]  = __builtin_amdgcn_mfma_f32_16x16x32_bf16(axi[kc], wrF, aI[os], 0, 0, 0);
      }
    }
#pragma unroll
    for (int os = 0; os < 4; ++os) {
      f32x4 R = aR1[os] - aR2[os];
      f32x4 I = aI[os];
      int ya = (os * 16 + lane15) * 24 + quad * 4;
      *(u32x2*)&ytR[ya] = u32x2{pkbf(R[0], R[1]), pkbf(R[2], R[3])};
      *(u32x2*)&ytI[ya] = u32x2{pkbf(I[0], I[1]), pkbf(I[2], I[3])};
    }
#pragma unroll
    for (int part = 0; part < 2; ++part) {
      const short* yt = part ? ytI : ytR;
#pragma unroll
      for (int h = 0; h < 2; ++h) {
        short8 unit = *(const short8*)&yt[l * 24 + h * 8];
        size_t line = (((size_t)(b * 5 + k) * 2 + part) * 16 + (q >> 1)) * 4 + (l >> 4);
        size_t idx = line * 64 + ((q & 1) * 2 + h) * 16 + (l & 15);
        yfrag[idx] = __builtin_bit_cast(u32x4, unit);
      }
    }
  }
}

// ---------------- k_main: out[b, i-tile(16)] — 1 wave, zero LDS.
// A(L) frags formed in registers from nontemporal lap loads * recomputed a;
// B(Y) frags read as coalesced 1KB lines from L2-resident yfrag.
__global__ __launch_bounds__(64, 2) void k_main(
    const float* __restrict__ lapr, const float* __restrict__ lapi,
    const float4* __restrict__ s4, const float4* __restrict__ stats,
    const float2* __restrict__ sj2, const u32x4* __restrict__ yfrag,
    const float* __restrict__ bar, const float* __restrict__ bai,
    const float* __restrict__ modbp,
    float* __restrict__ out_r, float* __restrict__ out_i)
{
  int g = blockIdx.x;
  int b = (g & 7) + ((g >> 8) << 3);   // XCD swizzle: same-b i-tiles on one XCD
  int it = (g >> 3) & 31;
  int l = threadIdx.x;
  int lane15 = l & 15, quad = l >> 4;
  int gi = it * 16 + lane15;

  float ba_r = bar[0], ba_i = bai[0], modb = modbp[0];
  float4 sv = s4[(size_t)b * 512 + gi];
  float4 st = stats[(size_t)b * 512 + gi];
  float sirb = sv.x + ba_r, siib = sv.y + ba_i;
  float maxr = st.x, rsr = st.y, maxi = st.z, rsi = st.w;

  f32x4 accR1[4], accR2[4], accI[4];
#pragma unroll
  for (int os = 0; os < 4; ++os) {
    accR1[os] = f32x4{0.f, 0.f, 0.f, 0.f};
    accR2[os] = f32x4{0.f, 0.f, 0.f, 0.f};
    accI[os] = f32x4{0.f, 0.f, 0.f, 0.f};
  }

  const size_t NN = (size_t)512 * 512;
  const float* lapr_b = lapr + ((size_t)b * 5 * 512 + gi) * 512;
  const float* lapi_b = lapi + ((size_t)b * 5 * 512 + gi) * 512;

  for (int js = 0; js < 16; ++js) {
    int jq = js * 32 + quad * 8;
    float2 sj[8];
#pragma unroll
    for (int e = 0; e < 8; ++e) sj[e] = sj2[(size_t)b * 512 + jq + e];
    f32x4 LRv[5][2], LIv[5][2];
#pragma unroll
    for (int k = 0; k < 5; ++k) {
      const f32x4* pr = (const f32x4*)(lapr_b + (size_t)k * NN + jq);
      const f32x4* pi_ = (const f32x4*)(lapi_b + (size_t)k * NN + jq);
      LRv[k][0] = __builtin_nontemporal_load(pr);
      LRv[k][1] = __builtin_nontemporal_load(pr + 1);
      LIv[k][0] = __builtin_nontemporal_load(pi_);
      LIv[k][1] = __builtin_nontemporal_load(pi_ + 1);
    }
    float ar[8], ai[8];
#pragma unroll
    for (int e = 0; e < 8; ++e) {
      float scr = sirb + sj[e].x;
      float sci = siib + sj[e].y;
      float mag = sqrtf(scr * scr + sci * sci);
      float sc = fmaxf(mag + modb, 0.f) * __builtin_amdgcn_rcpf(mag + EPSF);
      ar[e] = __expf(scr * sc - maxr) * rsr;
      ai[e] = __expf(sci * sc - maxi) * rsi;
    }
#pragma unroll
    for (int k = 0; k < 5; ++k) {
      const u32x4* y0 = yfrag + ((size_t)(b * 5 + k) * 128 + js * 4) * 64 + l;
      u32x4 bR[4], bI[4];
#pragma unroll
      for (int os = 0; os < 4; ++os) {
        bR[os] = y0[os * 64];
        bI[os] = y0[4096 + os * 64];
      }
      float lrv[8], liv[8];
#pragma unroll
      for (int h = 0; h < 2; ++h)
#pragma unroll
        for (int e2 = 0; e2 < 4; ++e2) {
          float grv = LRv[k][h][e2], giv = LIv[k][h][e2];
          int e = h * 4 + e2;
          lrv[e] = grv * ar[e] - giv * ai[e];
          liv[e] = grv * ai[e] + giv * ar[e];
        }
      short8 Ar = mk8(pkbf(lrv[0], lrv[1]), pkbf(lrv[2], lrv[3]), pkbf(lrv[4], lrv[5]), pkbf(lrv[6], lrv[7]));
      short8 Ai = mk8(pkbf(liv[0], liv[1]), pkbf(liv[2], liv[3]), pkbf(liv[4], liv[5]), pkbf(liv[6], liv[7]));
#pragma unroll
      for (int os = 0; os < 4; ++os) {
        short8 br8 = __builtin_bit_cast(short8, bR[os]);
        short8 bi8 = __builtin_bit_cast(short8, bI[os]);
        accR1[os] = __builtin_amdgcn_mfma_f32_16x16x32_bf16(Ar, br8, accR1[os], 0, 0, 0);
        accR2[os] = __builtin_amdgcn_mfma_f32_16x16x32_bf16(Ai, bi8, accR2[os], 0, 0, 0);
        accI[os]  = __builtin_amdgcn_mfma_f32_16x16x32_bf16(Ar, bi8, accI[os], 0, 0, 0);
        accI[os]  = __builtin_amdgcn_mfma_f32_16x16x32_bf16(Ai, br8, accI[os], 0, 0, 0);
      }
    }
  }
#pragma unroll
  for (int os = 0; os < 4; ++os) {
    f32x4 R = accR1[os] - accR2[os];
    f32x4 I = accI[os];
    int oc = os * 16 + lane15;
#pragma unroll
    for (int r = 0; r < 4; ++r) {
      size_t oidx = ((size_t)b * 512 + it * 16 + quad * 4 + r) * 64 + oc;
      out_r[oidx] = R[r];
      out_i[oidx] = I[r];
    }
  }
}

extern "C" void kernel_launch(void* const* d_in, const int* in_sizes, int n_in,
                              void* d_out, int out_size, void* d_ws, size_t ws_size,
                              hipStream_t stream) {
  const float* Xr = (const float*)d_in[0];
  const float* Xi = (const float*)d_in[1];
  const float* lapr = (const float*)d_in[2];
  const float* lapi = (const float*)d_in[3];
  const float* War = (const float*)d_in[4];
  const float* Wai = (const float*)d_in[5];
  const float* bar = (const float*)d_in[6];
  const float* bai = (const float*)d_in[7];
  const float* modb = (const float*)d_in[8];
  const float* Wr = (const float*)d_in[9];
  const float* Wi = (const float*)d_in[10];

  // ws layout: s4 384KB | stats 384KB | sj2 192KB | yfrag 30MB  (total ~31.7MB)
  char* wsb = (char*)d_ws;
  float4* s4 = (float4*)wsb;
  float4* stats = (float4*)(wsb + 393216);
  float2* sj2 = (float2*)(wsb + 786432);
  u32x4* yfrag = (u32x4*)(wsb + 983040);

  float* out_r = (float*)d_out;
  float* out_i = out_r + (size_t)48 * 512 * 64;

  k_s<<<768, 256, 0, stream>>>(Xr, Xi, War, Wai, s4, sj2);
  k_stats<<<768, 256, 0, stream>>>(s4, sj2, bar, bai, modb, stats);
  k_y<<<240, 256, 0, stream>>>(Xr, Xi, Wr, Wi, yfrag);
  k_main<<<1536, 64, 0, stream>>>(lapr, lapi, s4, stats, sj2, yfrag,
                                  bar, bai, modb, out_r, out_i);
}